// Round 2
// baseline (15833.525 us; speedup 1.0000x reference)
//
#include <hip/hip_runtime.h>
#include <stdint.h>

// Problem constants
#define BB   64
#define TT   512
#define HT   256
#define OO   128
#define GATES 1024   // 4*H
#define NQ   16      // gate-split: blocks per barrier group
#define JW   16      // hidden units per block (256/NQ)

__device__ __forceinline__ float sigmoidf_(float x) {
    return 1.0f / (1.0f + __expf(-x));
}

// ---------------------------------------------------------------------------
// Embedding gather + decoder_action output
__global__ __launch_bounds__(256) void embed_kernel(
    const int* __restrict__ actions, const float* __restrict__ emb_table,
    float* __restrict__ X, float* __restrict__ dact)
{
    int row = blockIdx.x;
    int t = row & (TT - 1);
    int id = (t == 0) ? 0 : actions[row - 1];
    X[(int64_t)row * HT + threadIdx.x] = emb_table[(int64_t)id * HT + threadIdx.x];
    if (threadIdx.x == 0) dact[row] = (float)actions[row];
}

// ---------------------------------------------------------------------------
// Repack Whh into register-load order for lstm_rec16.
// Wpack4[((l*NQ + q)*16 + i)*256 + tid] = float4 of Whh[l][256*g + JW*q + j][64*s + 4*i ..]
// where tid = s*64 + r', r' = g*16 + j.
// grid: 512 blocks x 256 (131072 float4s)
__global__ __launch_bounds__(256) void repack_whh_kernel(
    const float* __restrict__ Whh, float4* __restrict__ Wpack4)
{
    int fl = blockIdx.x * 256 + threadIdx.x;      // 0..131071
    int t2 = fl & 255;
    int i  = (fl >> 8) & 15;
    int q  = (fl >> 12) & 15;
    int l  = fl >> 16;
    int rp = t2 & 63;
    int s  = t2 >> 6;
    int g  = rp >> 4;
    int j  = rp & 15;
    int row = 256 * g + JW * q + j;
    int kb  = 64 * s + 4 * i;
    Wpack4[fl] = *(const float4*)(Whh + ((int64_t)(l * GATES + row)) * HT + kb);
}

// zero the barrier-flag array (re-poisoned to 0xAA before every launch)
__global__ __launch_bounds__(256) void zero_kernel(int* __restrict__ p, int n)
{
    int i = blockIdx.x * 256 + threadIdx.x;
    if (i < n) p[i] = 0;
}

// ---------------------------------------------------------------------------
// Generic fp32 tiled GEMM: C = act( A @ op(B) + bias1 + bias2 )
// BM=BN=128, BK=16, 256 threads, 8x8 per thread. Dims divisible.
template<bool TRANS_B, int ACT>
__global__ __launch_bounds__(256) void gemm128_kernel(
    const float* __restrict__ A, const float* __restrict__ Bm,
    float* __restrict__ C,
    int K, int lda, int ldb, int ldc,
    int64_t sA, int64_t sB, int64_t sC,
    const float* __restrict__ bias1, const float* __restrict__ bias2)
{
    constexpr int BM = 128, BN = 128, BK = 16;
    __shared__ __align__(16) float As[BK][BM + 4];
    __shared__ __align__(16) float Bs[BK][BN + 4];

    const int tid = threadIdx.x;
    const int m0 = blockIdx.y * BM;
    const int n0 = blockIdx.x * BN;
    A  += (int64_t)blockIdx.z * sA;
    Bm += (int64_t)blockIdx.z * sB;
    C  += (int64_t)blockIdx.z * sC;

    const int tm = tid & 15;
    const int tn = tid >> 4;

    float acc[8][8] = {};

    for (int k0 = 0; k0 < K; k0 += BK) {
        #pragma unroll
        for (int i = 0; i < 2; i++) {
            int idx = tid + i * 256;
            int ar = idx >> 2;
            int ak = (idx & 3) * 4;
            const float4 v = *(const float4*)(A + (int64_t)(m0 + ar) * lda + k0 + ak);
            As[ak + 0][ar] = v.x; As[ak + 1][ar] = v.y;
            As[ak + 2][ar] = v.z; As[ak + 3][ar] = v.w;
        }
        if (TRANS_B) {
            #pragma unroll
            for (int i = 0; i < 2; i++) {
                int idx = tid + i * 256;
                int br = idx >> 2;
                int bk = (idx & 3) * 4;
                const float4 v = *(const float4*)(Bm + (int64_t)(n0 + br) * ldb + k0 + bk);
                Bs[bk + 0][br] = v.x; Bs[bk + 1][br] = v.y;
                Bs[bk + 2][br] = v.z; Bs[bk + 3][br] = v.w;
            }
        } else {
            #pragma unroll
            for (int i = 0; i < 2; i++) {
                int idx = tid + i * 256;
                int bk = idx >> 5;
                int bn = (idx & 31) * 4;
                const float4 v = *(const float4*)(Bm + (int64_t)(k0 + bk) * ldb + n0 + bn);
                *(float4*)&Bs[bk][bn] = v;
            }
        }
        __syncthreads();

        #pragma unroll
        for (int k = 0; k < BK; k++) {
            float a[8], b[8];
            *(float4*)&a[0] = *(const float4*)&As[k][tm * 8];
            *(float4*)&a[4] = *(const float4*)&As[k][tm * 8 + 4];
            *(float4*)&b[0] = *(const float4*)&Bs[k][tn * 8];
            *(float4*)&b[4] = *(const float4*)&Bs[k][tn * 8 + 4];
            #pragma unroll
            for (int i = 0; i < 8; i++)
                #pragma unroll
                for (int j = 0; j < 8; j++)
                    acc[i][j] += a[i] * b[j];
        }
        __syncthreads();
    }

    float bv[8];
    #pragma unroll
    for (int j = 0; j < 8; j++) {
        int n = n0 + tn * 8 + j;
        float b = 0.0f;
        if (bias1) b += bias1[n];
        if (bias2) b += bias2[n];
        bv[j] = b;
    }
    #pragma unroll
    for (int i = 0; i < 8; i++) {
        int64_t m = m0 + tm * 8 + i;
        float o[8];
        #pragma unroll
        for (int j = 0; j < 8; j++) {
            float v = acc[i][j] + bv[j];
            if (ACT == 1) v = tanhf(v);
            o[j] = v;
        }
        *(float4*)(C + m * ldc + n0 + tn * 8)     = make_float4(o[0], o[1], o[2], o[3]);
        *(float4*)(C + m * ldc + n0 + tn * 8 + 4) = make_float4(o[4], o[5], o[6], o[7]);
    }
}

// ---------------------------------------------------------------------------
// LSTM recurrence, register-persistent weights, 16-way gate split, 2 batches
// per block. grid: 512 blocks x 256 threads. blockIdx.x = q*32 + bg so the 16
// blocks of group bg share (i%8) -> likely same XCD.
// Thread tid: r' = tid&63 (gate row within slice, r' = g*16+j), s = tid>>6
// (k-quarter). Holds w[16] float4 = W[row][64s..64s+63] in VGPRs.
__global__ __launch_bounds__(256) void lstm_rec16_kernel(
    const float* __restrict__ Ag,      // [B*T][1024] x@Wih^T + bih + bhh
    const float4* __restrict__ Wpack4, // this layer's packed slice base
    const float* __restrict__ h0,      // [B][256] this layer
    const float* __restrict__ c0,
    float* __restrict__ X, int ldx,    // h output, row b*T+t, col offset JW*q
    float* __restrict__ Hex,           // [2][64][256] exchange buffer
    int* __restrict__ cnt)             // [512][32] per-step flags (zeroed)
{
    const int tid = threadIdx.x;
    const int q  = blockIdx.x >> 5;    // 0..15
    const int bg = blockIdx.x & 31;    // 0..31
    const int b0 = bg * 2, b1 = bg * 2 + 1;

    __shared__ __align__(16) float hsh[2][HT];
    __shared__ float P[4][2][64];
    __shared__ float gl[2][64];

    // --- weights into registers (64 VGPRs)
    float4 w[16];
    const float4* wp = Wpack4 + (int64_t)q * 16 * 256 + tid;
    #pragma unroll
    for (int i = 0; i < 16; i++) w[i] = wp[i * 256];

    const int rp = tid & 63;
    const int s  = tid >> 6;

    // --- h init
    hsh[0][tid] = h0[b0 * HT + tid];
    hsh[1][tid] = h0[b1 * HT + tid];

    // --- gate-assembly thread mapping (tid < 128): bbg = which batch, rr = row
    const int bbg = tid >> 6;          // valid for tid<128
    const int rr  = tid & 63;
    const int gg2 = rr >> 4, jj = rr & 15;
    const float* Aptr = Ag + ((int64_t)((bbg ? b1 : b0)) * TT) * GATES
                           + 256 * gg2 + JW * q + jj;

    // --- updater mapping: tid<16 -> batch0, tid in [64,80) -> batch1
    int upd = -1, uj = 0;
    if (tid < JW)                       { upd = 0; uj = tid; }
    else if (tid >= 64 && tid < 64 + JW){ upd = 1; uj = tid - 64; }
    float c_reg = 0.0f;
    if (upd >= 0) c_reg = c0[(upd ? b1 : b0) * HT + JW * q + uj];

    __syncthreads();

    const float4* hsh4_0 = (const float4*)hsh[0];
    const float4* hsh4_1 = (const float4*)hsh[1];

    for (int t = 0; t < TT; t++) {
        float Aval = 0.0f;
        if (tid < 128) Aval = Aptr[(int64_t)t * GATES];   // hides under dot

        float acc0 = 0.0f, acc1 = 0.0f;
        #pragma unroll
        for (int i = 0; i < 16; i++) {
            float4 h40 = hsh4_0[s * 16 + i];   // broadcast (wave-uniform addr)
            float4 h41 = hsh4_1[s * 16 + i];
            float4 wv = w[i];
            acc0 += wv.x * h40.x + wv.y * h40.y + wv.z * h40.z + wv.w * h40.w;
            acc1 += wv.x * h41.x + wv.y * h41.y + wv.z * h41.z + wv.w * h41.w;
        }
        P[s][0][rp] = acc0;
        P[s][1][rp] = acc1;
        __syncthreads();

        if (tid < 128) {
            float gsum = P[0][bbg][rr] + P[1][bbg][rr] + P[2][bbg][rr] + P[3][bbg][rr] + Aval;
            gl[bbg][rr] = gsum;
        }
        __syncthreads();

        if (upd >= 0) {
            float gi = gl[upd][uj];
            float gf = gl[upd][JW + uj];
            float gc = gl[upd][2 * JW + uj];
            float go = gl[upd][3 * JW + uj];
            c_reg = sigmoidf_(gf) * c_reg + sigmoidf_(gi) * tanhf(gc);
            float h = sigmoidf_(go) * tanhf(c_reg);
            int bglob = upd ? b1 : b0;
            X[((int64_t)bglob * TT + t) * ldx + JW * q + uj] = h;
            if (t + 1 < TT) {
                __hip_atomic_store(&Hex[((t & 1) * BB + bglob) * HT + JW * q + uj], h,
                                   __ATOMIC_RELAXED, __HIP_MEMORY_SCOPE_AGENT);
            }
        }
        if (t + 1 == TT) break;

        // barrier: all 16 blocks of group bg published their h slices.
        // __syncthreads drains vmcnt(0) in every wave -> Hex stores are at the
        // coherence point before thread 0 bumps the flag.
        __syncthreads();
        if (tid == 0) {
            int* flag = &cnt[t * 32 + bg];
            __hip_atomic_fetch_add(flag, 1, __ATOMIC_RELEASE, __HIP_MEMORY_SCOPE_AGENT);
            while (__hip_atomic_load(flag, __ATOMIC_ACQUIRE, __HIP_MEMORY_SCOPE_AGENT) < NQ)
                __builtin_amdgcn_s_sleep(1);
        }
        __syncthreads();

        // refill full h for both batches from the exchange buffer
        {
            const float* hx = Hex + (t & 1) * BB * HT;
            float v0 = __hip_atomic_load(&hx[b0 * HT + tid], __ATOMIC_RELAXED, __HIP_MEMORY_SCOPE_AGENT);
            float v1 = __hip_atomic_load(&hx[b1 * HT + tid], __ATOMIC_RELAXED, __HIP_MEMORY_SCOPE_AGENT);
            hsh[0][tid] = v0;
            hsh[1][tid] = v1;
        }
        __syncthreads();
    }
}

// ---------------------------------------------------------------------------
__global__ __launch_bounds__(256) void softmax512_kernel(float* __restrict__ S)
{
    int row = blockIdx.x * 4 + (threadIdx.x >> 6);
    int lane = threadIdx.x & 63;
    float* p = S + (int64_t)row * 512 + lane * 8;
    float4 v0 = *(float4*)p;
    float4 v1 = *(float4*)(p + 4);
    float m = fmaxf(fmaxf(fmaxf(v0.x, v0.y), fmaxf(v0.z, v0.w)),
                    fmaxf(fmaxf(v1.x, v1.y), fmaxf(v1.z, v1.w)));
    #pragma unroll
    for (int off = 32; off; off >>= 1) m = fmaxf(m, __shfl_xor(m, off));
    v0.x = __expf(v0.x - m); v0.y = __expf(v0.y - m);
    v0.z = __expf(v0.z - m); v0.w = __expf(v0.w - m);
    v1.x = __expf(v1.x - m); v1.y = __expf(v1.y - m);
    v1.z = __expf(v1.z - m); v1.w = __expf(v1.w - m);
    float s = v0.x + v0.y + v0.z + v0.w + v1.x + v1.y + v1.z + v1.w;
    #pragma unroll
    for (int off = 32; off; off >>= 1) s += __shfl_xor(s, off);
    float inv = 1.0f / s;
    v0.x *= inv; v0.y *= inv; v0.z *= inv; v0.w *= inv;
    v1.x *= inv; v1.y *= inv; v1.z *= inv; v1.w *= inv;
    *(float4*)p = v0;
    *(float4*)(p + 4) = v1;
}

__global__ __launch_bounds__(256) void values_kernel(
    const float* __restrict__ Q, const float* __restrict__ L, float* __restrict__ V)
{
    int row = blockIdx.x * 4 + (threadIdx.x >> 6);
    int lane = threadIdx.x & 63;
    float2 q = *(const float2*)(Q + (int64_t)row * OO + lane * 2);
    float2 l = *(const float2*)(L + (int64_t)row * OO + lane * 2);
    float s = q.x * l.x + q.y * l.y;
    #pragma unroll
    for (int off = 32; off; off >>= 1) s += __shfl_xor(s, off);
    if (lane == 0) V[row] = s;
}

// ---------------------------------------------------------------------------
extern "C" void kernel_launch(void* const* d_in, const int* in_sizes, int n_in,
                              void* d_out, int out_size, void* d_ws, size_t ws_size,
                              hipStream_t stream)
{
    const float* enc      = (const float*)d_in[0];
    const float* h0       = (const float*)d_in[1];
    const float* c0       = (const float*)d_in[2];
    const int*   actions  = (const int*)  d_in[3];
    const float* emb_t    = (const float*)d_in[4];
    const float* Wih      = (const float*)d_in[5];
    const float* Whh      = (const float*)d_in[6];
    const float* bih      = (const float*)d_in[7];
    const float* bhh      = (const float*)d_in[8];
    const float* W_attn   = (const float*)d_in[9];
    const float* b_attn   = (const float*)d_in[10];
    const float* W_concat = (const float*)d_in[11];
    const float* b_concat = (const float*)d_in[12];
    const float* W_out    = (const float*)d_in[13];
    const float* W_critic = (const float*)d_in[14];
    const float* b_critic = (const float*)d_in[15];
    (void)in_sizes; (void)n_in; (void)out_size; (void)ws_size;

    const int M = BB * TT;                 // 32768

    float* out    = (float*)d_out;
    float* dact   = out;
    float* logits = out + M;
    float* values = out + M + (int64_t)M * OO;

    // Workspace arena (floats), 256 MiB total:
    //   gates : 33,554,432   (A; later scores(64MB) then qv)
    //   xbuf  :  8,388,608   (emb -> X1 -> dec)
    //   cat   : 16,777,216   ([out | ctx] row stride 512)
    //   keysR :  8,388,608   (Wpack+Hex+cnt during LSTM; keys after)
    float* ws    = (float*)d_ws;
    float* gates = ws;
    float* xbuf  = ws + 33554432;
    float* cat   = ws + 41943040;
    float* keysR = ws + 58720256;
    float* keys  = keysR;
    float4* Wpack4 = (float4*)keysR;              // 131072 float4 = 2 MB
    float* Hex   = keysR + 2097152;               // 2*64*256 = 32768 floats
    int*   cnt   = (int*)(keysR + 2097152 + 32768); // 512*32*2 layers? -> per layer offset
    float* scores = gates;
    float* qv     = gates;
    float* dec    = xbuf;

    const int64_t LWP = 65536;              // float4s per layer in Wpack
    const int CNT_PER_LAYER = TT * 32;      // 16384 ints

    // 1) embedding + decoder_action
    hipLaunchKernelGGL(embed_kernel, dim3(M), dim3(256), 0, stream,
                       actions, emb_t, xbuf, dact);
    // 2) repack Whh for register-resident layout
    hipLaunchKernelGGL(repack_whh_kernel, dim3(512), dim3(256), 0, stream,
                       Whh, Wpack4);
    // 3) zero the barrier flags (both layers): 32768 ints
    hipLaunchKernelGGL(zero_kernel, dim3(128), dim3(256), 0, stream,
                       cnt, 2 * CNT_PER_LAYER);
    // 4) layer-0 input GEMM
    hipLaunchKernelGGL((gemm128_kernel<true, 0>), dim3(8, 256, 1), dim3(256), 0, stream,
                       xbuf, Wih, gates, HT, HT, HT, GATES,
                       (int64_t)0, (int64_t)0, (int64_t)0, bih, bhh);
    // 5) layer-0 recurrence -> X1 (xbuf, ldx=256)
    hipLaunchKernelGGL(lstm_rec16_kernel, dim3(512), dim3(256), 0, stream,
                       gates, Wpack4, h0, c0, xbuf, HT, Hex, cnt);
    // 6) layer-1 input GEMM
    hipLaunchKernelGGL((gemm128_kernel<true, 0>), dim3(8, 256, 1), dim3(256), 0, stream,
                       xbuf, Wih + (int64_t)GATES * HT, gates, HT, HT, HT, GATES,
                       (int64_t)0, (int64_t)0, (int64_t)0, bih + GATES, bhh + GATES);
    // 7) layer-1 recurrence -> cat[:, 0:256] (ldx=512)
    hipLaunchKernelGGL(lstm_rec16_kernel, dim3(512), dim3(256), 0, stream,
                       gates, Wpack4 + LWP, h0 + BB * HT, c0 + BB * HT, cat, 2 * HT,
                       Hex, cnt + CNT_PER_LAYER);
    // 8) keys = enc @ W_attn^T + b_attn   (overwrites Wpack/Hex/cnt region)
    hipLaunchKernelGGL((gemm128_kernel<true, 0>), dim3(2, 256, 1), dim3(256), 0, stream,
                       enc, W_attn, keys, HT, HT, HT, HT,
                       (int64_t)0, (int64_t)0, (int64_t)0, b_attn, (const float*)nullptr);
    // 9) scores[b] = out[b] @ keys[b]^T
    hipLaunchKernelGGL((gemm128_kernel<true, 0>), dim3(4, 4, BB), dim3(256), 0, stream,
                       cat, keys, scores, HT, 2 * HT, HT, TT,
                       (int64_t)TT * 2 * HT, (int64_t)TT * HT, (int64_t)TT * TT,
                       (const float*)nullptr, (const float*)nullptr);
    // 10) softmax
    hipLaunchKernelGGL(softmax512_kernel, dim3(M / 4), dim3(256), 0, stream, scores);
    // 11) ctx[b] = P[b] @ enc[b] -> cat[:,256:]
    hipLaunchKernelGGL((gemm128_kernel<false, 0>), dim3(2, 4, BB), dim3(256), 0, stream,
                       scores, enc, cat + HT, TT, TT, HT, 2 * HT,
                       (int64_t)TT * TT, (int64_t)TT * HT, (int64_t)TT * 2 * HT,
                       (const float*)nullptr, (const float*)nullptr);
    // 12) dec = tanh(cat @ W_concat^T + b_concat)
    hipLaunchKernelGGL((gemm128_kernel<true, 1>), dim3(2, 256, 1), dim3(256), 0, stream,
                       cat, W_concat, dec, 2 * HT, 2 * HT, 2 * HT, HT,
                       (int64_t)0, (int64_t)0, (int64_t)0, b_concat, (const float*)nullptr);
    // 13) logits = dec @ W_out^T
    hipLaunchKernelGGL((gemm128_kernel<true, 0>), dim3(1, 256, 1), dim3(256), 0, stream,
                       dec, W_out, logits, HT, HT, HT, OO,
                       (int64_t)0, (int64_t)0, (int64_t)0,
                       (const float*)nullptr, (const float*)nullptr);
    // 14) qv = logits @ W_critic^T + b_critic
    hipLaunchKernelGGL((gemm128_kernel<true, 0>), dim3(1, 256, 1), dim3(256), 0, stream,
                       logits, W_critic, qv, OO, OO, OO, OO,
                       (int64_t)0, (int64_t)0, (int64_t)0, b_critic, (const float*)nullptr);
    // 15) values
    hipLaunchKernelGGL(values_kernel, dim3(M / 4), dim3(256), 0, stream,
                       qv, logits, values);
}